// Round 1
// baseline (225.729 us; speedup 1.0000x reference)
//
#include <hip/hip_runtime.h>

#define SIGMA 10.0f
#define RHO   28.0f
#define DT    0.01f
static constexpr float BETA = (float)(8.0 / 3.0);

__device__ __forceinline__ void lorenz_f(float x, float y, float z,
                                         float& dx, float& dy, float& dz) {
    dx = SIGMA * (y - x);
    dy = x * (RHO - z) - y;
    dz = x * y - BETA * z;
}

__global__ __launch_bounds__(256)
void lya_spec_kernel(const float* __restrict__ xin,
                     const float* __restrict__ ts,
                     float* __restrict__ out,
                     int B, int T) {
    int b = blockIdx.x * blockDim.x + threadIdx.x;
    if (b >= B) return;

    float x = xin[b];
    float y = xin[B + b];
    float z = xin[2 * B + b];

    // Q rows (row-major), init = I
    float q00 = 1.f, q01 = 0.f, q02 = 0.f;
    float q10 = 0.f, q11 = 1.f, q12 = 0.f;
    float q20 = 0.f, q21 = 0.f, q22 = 1.f;

    float l0 = 0.f, l1 = 0.f, l2 = 0.f;

    for (int it = 0; it < T; ++it) {
        const float t = ts[it];   // uniform -> scalar load

        // ---- RK4 (faithful to reference bug: k4 at x + dt*k2) ----
        float k1x, k1y, k1z, k2x, k2y, k2z, k3x, k3y, k3z, k4x, k4y, k4z;
        lorenz_f(x, y, z, k1x, k1y, k1z);
        const float h = DT * 0.5f;
        lorenz_f(x + h * k1x, y + h * k1y, z + h * k1z, k2x, k2y, k2z);
        lorenz_f(x + h * k2x, y + h * k2y, z + h * k2z, k3x, k3y, k3z);
        lorenz_f(x + DT * k2x, y + DT * k2y, z + DT * k2z, k4x, k4y, k4z);
        const float sixth = (float)(1.0 / 6.0);
        x = x + DT * (k1x + 2.0f * k2x + 2.0f * k3x + k4x) * sixth;
        y = y + DT * (k1y + 2.0f * k2y + 2.0f * k3y + k4y) * sixth;
        z = z + DT * (k1z + 2.0f * k2z + 2.0f * k3z + k4z) * sixth;

        // ---- tangent propagator J = I + dt * Jac(x) ----
        const float j00 = 1.0f + DT * (-SIGMA);
        const float j01 = DT * SIGMA;
        // j02 = 0
        const float j10 = DT * (RHO - z);
        const float j11 = 1.0f + DT * (-1.0f);
        const float j12 = DT * (-x);
        const float j20 = DT * y;
        const float j21 = DT * x;
        const float j22 = 1.0f + DT * (-BETA);

        // ---- Q = J @ Q (per trajectory 3x3) ----
        float n00 = j00 * q00 + j01 * q10;
        float n01 = j00 * q01 + j01 * q11;
        float n02 = j00 * q02 + j01 * q12;
        float n10 = j10 * q00 + j11 * q10 + j12 * q20;
        float n11 = j10 * q01 + j11 * q11 + j12 * q21;
        float n12 = j10 * q02 + j11 * q12 + j12 * q22;
        float n20 = j20 * q00 + j21 * q10 + j22 * q20;
        float n21 = j20 * q01 + j21 * q11 + j22 * q21;
        float n22 = j20 * q02 + j21 * q12 + j22 * q22;

        // ---- MGS over rows (in-place torch semantics) ----
        // row0 unchanged
        const float d00 = n00 * n00 + n01 * n01 + n02 * n02;

        // row1 -= (r0.r1 / r0.r0) * r0
        const float d01 = n00 * n10 + n01 * n11 + n02 * n12;
        const float c01 = d01 / d00;
        float r10 = n10 - c01 * n00;
        float r11 = n11 - c01 * n01;
        float r12 = n12 - c01 * n02;

        // row2 -= (r0.r2 / r0.r0) * r0 ; then -= (r1.r2 / r1.r1) * r1
        const float d02 = n00 * n20 + n01 * n21 + n02 * n22;
        const float c02 = d02 / d00;
        float a0 = n20 - c02 * n00;
        float a1 = n21 - c02 * n01;
        float a2 = n22 - c02 * n02;

        const float d11 = r10 * r10 + r11 * r11 + r12 * r12;
        const float d1a = r10 * a0 + r11 * a1 + r12 * a2;
        const float c12 = d1a / d11;
        float r20 = a0 - c12 * r10;
        float r21 = a1 - c12 * r11;
        float r22 = a2 - c12 * r12;

        // ---- row norms (reuse dots: identical algebra to recompute) ----
        const float d22 = r20 * r20 + r21 * r21 + r22 * r22;
        const float nrm0 = sqrtf(d00);
        const float nrm1 = sqrtf(d11);
        const float nrm2 = sqrtf(d22);

        q00 = n00 / nrm0; q01 = n01 / nrm0; q02 = n02 / nrm0;
        q10 = r10 / nrm1; q11 = r11 / nrm1; q12 = r12 / nrm1;
        q20 = r20 / nrm2; q21 = r21 / nrm2; q22 = r22 / nrm2;

        // ---- running Lyapunov average ----
        const float denom = t + DT;
        l0 = (l0 * t + logf(nrm0)) / denom;
        l1 = (l1 * t + logf(nrm1)) / denom;
        l2 = (l2 * t + logf(nrm2)) / denom;
    }

    // outputs: lya [3,B] then xf [3,B]
    out[b]         = l0;
    out[B + b]     = l1;
    out[2 * B + b] = l2;
    out[3 * B + b] = x;
    out[4 * B + b] = y;
    out[5 * B + b] = z;
}

extern "C" void kernel_launch(void* const* d_in, const int* in_sizes, int n_in,
                              void* d_out, int out_size, void* d_ws, size_t ws_size,
                              hipStream_t stream) {
    const float* xin = (const float*)d_in[0];
    const float* ts  = (const float*)d_in[1];
    float* out = (float*)d_out;

    const int B = in_sizes[0] / 3;   // x is [3, B]
    const int T = in_sizes[1];       // 64

    const int block = 256;
    const int grid = (B + block - 1) / block;
    lya_spec_kernel<<<grid, block, 0, stream>>>(xin, ts, out, B, T);
}

// Round 2
// 130.596 us; speedup vs baseline: 1.7285x; 1.7285x over previous
//
#include <hip/hip_runtime.h>

#define SIGMA 10.0f
#define RHO   28.0f
#define DT    0.01f
static constexpr float BETA = (float)(8.0 / 3.0);
// ln(sqrt(d)) = 0.5 * ln(2) * log2(d)
#define HALF_LN2 0.34657359028f

__device__ __forceinline__ void lorenz_f(float x, float y, float z,
                                         float& dx, float& dy, float& dz) {
    dx = SIGMA * (y - x);
    dy = x * (RHO - z) - y;
    dz = x * y - BETA * z;
}

__global__ __launch_bounds__(256)
void lya_spec_kernel(const float* __restrict__ xin,
                     const float* __restrict__ ts,
                     float* __restrict__ out,
                     int B, int T) {
    int b = blockIdx.x * blockDim.x + threadIdx.x;
    if (b >= B) return;

    float x = xin[b];
    float y = xin[B + b];
    float z = xin[2 * B + b];

    // Q rows (row-major), init = I
    float q00 = 1.f, q01 = 0.f, q02 = 0.f;
    float q10 = 0.f, q11 = 1.f, q12 = 0.f;
    float q20 = 0.f, q21 = 0.f, q22 = 1.f;

    float l0 = 0.f, l1 = 0.f, l2 = 0.f;

    for (int it = 0; it < T; ++it) {
        const float t = ts[it];   // uniform -> scalar load

        // ---- RK4 (faithful to reference bug: k4 at x + dt*k2) ----
        float k1x, k1y, k1z, k2x, k2y, k2z, k3x, k3y, k3z, k4x, k4y, k4z;
        lorenz_f(x, y, z, k1x, k1y, k1z);
        const float h = DT * 0.5f;
        lorenz_f(x + h * k1x, y + h * k1y, z + h * k1z, k2x, k2y, k2z);
        lorenz_f(x + h * k2x, y + h * k2y, z + h * k2z, k3x, k3y, k3z);
        lorenz_f(x + DT * k2x, y + DT * k2y, z + DT * k2z, k4x, k4y, k4z);
        const float sixth = (float)(1.0 / 6.0);
        x = x + DT * (k1x + 2.0f * k2x + 2.0f * k3x + k4x) * sixth;
        y = y + DT * (k1y + 2.0f * k2y + 2.0f * k3y + k4y) * sixth;
        z = z + DT * (k1z + 2.0f * k2z + 2.0f * k3z + k4z) * sixth;

        // ---- tangent propagator J = I + dt * Jac(x) ----
        const float j00 = 1.0f + DT * (-SIGMA);
        const float j01 = DT * SIGMA;
        // j02 = 0
        const float j10 = DT * (RHO - z);
        const float j11 = 1.0f + DT * (-1.0f);
        const float j12 = DT * (-x);
        const float j20 = DT * y;
        const float j21 = DT * x;
        const float j22 = 1.0f + DT * (-BETA);

        // ---- Q = J @ Q (per trajectory 3x3) ----
        float n00 = j00 * q00 + j01 * q10;
        float n01 = j00 * q01 + j01 * q11;
        float n02 = j00 * q02 + j01 * q12;
        float n10 = j10 * q00 + j11 * q10 + j12 * q20;
        float n11 = j10 * q01 + j11 * q11 + j12 * q21;
        float n12 = j10 * q02 + j11 * q12 + j12 * q22;
        float n20 = j20 * q00 + j21 * q10 + j22 * q20;
        float n21 = j20 * q01 + j21 * q11 + j22 * q21;
        float n22 = j20 * q02 + j21 * q12 + j22 * q22;

        // ---- MGS over rows (in-place torch semantics) ----
        // fast hw approximations: v_rcp_f32 / v_rsq_f32 / v_log_f32 (~1 ulp)
        // row0 unchanged
        const float d00 = n00 * n00 + n01 * n01 + n02 * n02;
        const float rd00 = __builtin_amdgcn_rcpf(d00);

        // row1 -= (r0.r1 / r0.r0) * r0
        const float d01 = n00 * n10 + n01 * n11 + n02 * n12;
        const float c01 = d01 * rd00;
        float r10 = n10 - c01 * n00;
        float r11 = n11 - c01 * n01;
        float r12 = n12 - c01 * n02;

        // row2 -= (r0.r2 / r0.r0) * r0 ; then -= (r1.r2 / r1.r1) * r1
        const float d02 = n00 * n20 + n01 * n21 + n02 * n22;
        const float c02 = d02 * rd00;
        float a0 = n20 - c02 * n00;
        float a1 = n21 - c02 * n01;
        float a2 = n22 - c02 * n02;

        const float d11 = r10 * r10 + r11 * r11 + r12 * r12;
        const float d1a = r10 * a0 + r11 * a1 + r12 * a2;
        const float c12 = d1a * __builtin_amdgcn_rcpf(d11);
        float r20 = a0 - c12 * r10;
        float r21 = a1 - c12 * r11;
        float r22 = a2 - c12 * r12;

        const float d22 = r20 * r20 + r21 * r21 + r22 * r22;

        // ---- normalize rows via rsqrt-multiply ----
        const float rn0 = __builtin_amdgcn_rsqf(d00);
        const float rn1 = __builtin_amdgcn_rsqf(d11);
        const float rn2 = __builtin_amdgcn_rsqf(d22);

        q00 = n00 * rn0; q01 = n01 * rn0; q02 = n02 * rn0;
        q10 = r10 * rn1; q11 = r11 * rn1; q12 = r12 * rn1;
        q20 = r20 * rn2; q21 = r21 * rn2; q22 = r22 * rn2;

        // ---- log(norm) = 0.5*ln2*log2(d) ----
        const float lg0 = __builtin_amdgcn_logf(d00) * HALF_LN2;
        const float lg1 = __builtin_amdgcn_logf(d11) * HALF_LN2;
        const float lg2 = __builtin_amdgcn_logf(d22) * HALF_LN2;

        // ---- running Lyapunov average: l = l*(t/(t+dt)) + lg/(t+dt) ----
        const float rden = __builtin_amdgcn_rcpf(t + DT);
        const float alpha = t * rden;
        l0 = fmaf(l0, alpha, lg0 * rden);
        l1 = fmaf(l1, alpha, lg1 * rden);
        l2 = fmaf(l2, alpha, lg2 * rden);
    }

    // outputs: lya [3,B] then xf [3,B]
    out[b]         = l0;
    out[B + b]     = l1;
    out[2 * B + b] = l2;
    out[3 * B + b] = x;
    out[4 * B + b] = y;
    out[5 * B + b] = z;
}

extern "C" void kernel_launch(void* const* d_in, const int* in_sizes, int n_in,
                              void* d_out, int out_size, void* d_ws, size_t ws_size,
                              hipStream_t stream) {
    const float* xin = (const float*)d_in[0];
    const float* ts  = (const float*)d_in[1];
    float* out = (float*)d_out;

    const int B = in_sizes[0] / 3;   // x is [3, B]
    const int T = in_sizes[1];       // 64

    const int block = 256;
    const int grid = (B + block - 1) / block;
    lya_spec_kernel<<<grid, block, 0, stream>>>(xin, ts, out, B, T);
}